// Round 9
// baseline (129.598 us; speedup 1.0000x reference)
//
#include <hip/hip_runtime.h>
#include <float.h>

using v2f = __attribute__((ext_vector_type(2))) float;
using v4f = __attribute__((ext_vector_type(4))) float;

#define EMB 10
#define STATE 20
#define HIDDEN 40
#define NPROJ 2490
#define WAVES 16
#define ITEMS 128           // items per scan block = 64 lanes x IPL(2)

// LDS-staged region: pairs [703,1245) (slices 9..15), 542 pairs.
#define LDS_P0     703
#define LDS_PAIRS  542
#define LDS_FLOATS (LDS_PAIRS * 20)       // 10840 floats = 43.36 KB
#define LDS_V4     (LDS_FLOATS / 4)       // 2710
#define LDS_FBASE  (LDS_P0 * 20)          // 14060 (float offset in pemb)

// ============================ MLP kernel =================================
// One thread = one item. Writes the 10 layer-2 outputs per item to ws.
__global__ __launch_bounds__(256, 4) void mlp_kernel(
    const int* __restrict__ wid, const int* __restrict__ pid,
    const float* __restrict__ wemb, const float* __restrict__ pemb,
    const float* __restrict__ W1, const float* __restrict__ b1,
    const float* __restrict__ W2, const float* __restrict__ b2,
    float* __restrict__ ws)
{
    const int b = blockIdx.x * 256 + threadIdx.x;

    const int wi = wid[b];
    const int pi = pid[b];
    const float* __restrict__ wr = wemb + wi * EMB;
    const float* __restrict__ pr = pemb + pi * EMB;
    v2f x2[STATE / 2];
    #pragma unroll
    for (int k = 0; k < EMB / 2; ++k) x2[k] = *(const v2f*)(wr + 2 * k);
    #pragma unroll
    for (int k = 0; k < EMB / 2; ++k) x2[EMB / 2 + k] = *(const v2f*)(pr + 2 * k);

    float hb[HIDDEN];
    #pragma unroll 4
    for (int j = 0; j < HIDDEN; ++j) {
        const v2f* w1r = (const v2f*)(W1 + j * STATE);
        v2f a = w1r[0] * x2[0];
        #pragma unroll
        for (int k = 1; k < STATE / 2; ++k) a += w1r[k] * x2[k];
        hb[j] = fmaxf(a.x + a.y + b1[j], 0.0f);
    }
    v2f h2[HIDDEN / 2];
    #pragma unroll
    for (int k = 0; k < HIDDEN / 2; ++k) h2[k] = (v2f){hb[2 * k], hb[2 * k + 1]};

    v2f* wout = (v2f*)(ws + b * EMB);
    #pragma unroll
    for (int d = 0; d < EMB; d += 2) {
        const v2f* w2r0 = (const v2f*)(W2 + d * HIDDEN);
        const v2f* w2r1 = (const v2f*)(W2 + (d + 1) * HIDDEN);
        v2f a0 = w2r0[0] * h2[0];
        v2f a1 = w2r1[0] * h2[0];
        #pragma unroll
        for (int k = 1; k < HIDDEN / 2; ++k) { a0 += w2r0[k] * h2[k]; a1 += w2r1[k] * h2[k]; }
        wout[d / 2] = (v2f){a0.x + a0.y + b2[d], a1.x + a1.y + b2[d + 1]};
    }
}

// ============================ scan kernel ================================
// Pure-scalar inner loop (r8-proven): wave-uniform table scalar feeds each
// v_fma_f32 directly as its one SGPR (or LDS-broadcast) operand.
// Accumulation order bitwise-identical to rounds 0-8 (even/odd chains + add).
__device__ __forceinline__ void score_row(const float* __restrict__ tr, int row,
                                          const float w0[10], const float w1[10],
                                          float best[2], int bidx[2]) {
    float t0 = tr[0], t1 = tr[1], t2 = tr[2], t3 = tr[3], t4 = tr[4];
    float t5 = tr[5], t6 = tr[6], t7 = tr[7], t8 = tr[8], t9 = tr[9];

    float e0 = t0 * w0[0];
    float o0 = t1 * w0[1];
    e0 = fmaf(t2, w0[2], e0);  o0 = fmaf(t3, w0[3], o0);
    e0 = fmaf(t4, w0[4], e0);  o0 = fmaf(t5, w0[5], o0);
    e0 = fmaf(t6, w0[6], e0);  o0 = fmaf(t7, w0[7], o0);
    e0 = fmaf(t8, w0[8], e0);  o0 = fmaf(t9, w0[9], o0);
    float s0 = e0 + o0;

    float e1 = t0 * w1[0];
    float o1 = t1 * w1[1];
    e1 = fmaf(t2, w1[2], e1);  o1 = fmaf(t3, w1[3], o1);
    e1 = fmaf(t4, w1[4], e1);  o1 = fmaf(t5, w1[5], o1);
    e1 = fmaf(t6, w1[6], e1);  o1 = fmaf(t7, w1[7], o1);
    e1 = fmaf(t8, w1[8], e1);  o1 = fmaf(t9, w1[9], o1);
    float s1 = e1 + o1;

    if (s0 > best[0]) { best[0] = s0; bidx[0] = row; }
    if (s1 > best[1]) { best[1] = s1; bidx[1] = row; }
}

// SMEM-path slice: constant bounds -> uniform p -> s_load pipelining.
template <int P0, int P1>
__device__ __forceinline__ void scan_range(const float* __restrict__ tblf,
                                           const float w0[10], const float w1[10],
                                           float best[2], int bidx[2]) {
    const float* t = tblf + P0 * 20;
    #pragma unroll 4
    for (int p = P0; p < P1; ++p, t += 20) {
        score_row(t,      2 * p,     w0, w1, best, bidx);
        score_row(t + 10, 2 * p + 1, w0, w1, best, bidx);
    }
}

// LDS-path slice: same loop over the staged copy; uniform address ->
// ds_read broadcast on the LGKM/DS pipe instead of the SMEM pipe.
template <int P0, int P1>
__device__ __forceinline__ void scan_range_lds(const float* lt,
                                               const float w0[10], const float w1[10],
                                               float best[2], int bidx[2]) {
    const float* t = lt + (P0 - LDS_P0) * 20;
    #pragma unroll 4
    for (int p = P0; p < P1; ++p, t += 20) {
        score_row(t,      2 * p,     w0, w1, best, bidx);
        score_row(t + 10, 2 * p + 1, w0, w1, best, bidx);
    }
}

// 1024 threads = 16 waves, 128 items per block (lane l owns items l, 64+l).
// DUAL-PATH table read: waves 0-8 stream their slices via s_load (SMEM pipe),
// waves 9-15 via an LDS-staged copy (DS pipe) -> per-pipe demand ~halved at
// unchanged occupancy (59.7 KB LDS < 64 KB static -> still 2 blocks/CU).
__global__ __launch_bounds__(1024, 8) void scan_kernel(
    const float* __restrict__ pemb, const float* __restrict__ ws,
    int* __restrict__ out)
{
    __shared__ float lt[LDS_FLOATS];    // 43.36 KB staged table region
    __shared__ float sb[WAVES][ITEMS];  // 8 KB
    __shared__ int   si[WAVES][ITEMS];  // 8 KB

    const int tid  = threadIdx.x;
    const int lane = tid & 63;
    const int wave = tid >> 6;
    const int itemBase = blockIdx.x * ITEMS;

    const float* __restrict__ tblf = pemb;

    // ---- cooperative staging of pairs [703,1245) into LDS ----
    {
        const v4f* src4 = (const v4f*)__builtin_assume_aligned(pemb + LDS_FBASE, 16);
        v4f* dst4 = (v4f*)lt;
        #pragma unroll
        for (int j = tid; j < LDS_V4; j += 1024) dst4[j] = src4[j];
    }

    // ---- per-lane weights for its 2 items (overlaps staging latency) ----
    float w0[10], w1[10];
    {
        const v4f* s0 = (const v4f*)(ws + (itemBase + lane) * EMB);
        const v2f* s0t = (const v2f*)(ws + (itemBase + lane) * EMB + 8);
        v4f a = s0[0], b = s0[1]; v2f c = s0t[0];
        w0[0]=a.x; w0[1]=a.y; w0[2]=a.z; w0[3]=a.w;
        w0[4]=b.x; w0[5]=b.y; w0[6]=b.z; w0[7]=b.w;
        w0[8]=c.x; w0[9]=c.y;
        const v4f* s1 = (const v4f*)(ws + (itemBase + 64 + lane) * EMB);
        const v2f* s1t = (const v2f*)(ws + (itemBase + 64 + lane) * EMB + 8);
        v4f d = s1[0], e = s1[1]; v2f f = s1t[0];
        w1[0]=d.x; w1[1]=d.y; w1[2]=d.z; w1[3]=d.w;
        w1[4]=e.x; w1[5]=e.y; w1[6]=e.z; w1[7]=e.w;
        w1[8]=f.x; w1[9]=f.y;
    }
    __syncthreads();

    float best[2];
    int   bidx[2];
    #pragma unroll
    for (int g = 0; g < 2; ++g) { best[g] = -FLT_MAX; bidx[g] = 1; }

    if (wave == 0) {
        // row 1 alone (row 0 excluded from the table)
        score_row(pemb + 10, 1, w0, w1, best, bidx);
    }

    // pairs p in [1,1245): rows (2p,2p+1). 16 constant-bound slices in
    // ascending order (0-11: 78 pairs, 12-15: 77). Waves 0-8: SMEM path;
    // waves 9-15: LDS path. Same values, same compare order -> same ties.
    switch (wave) {
        case  0: scan_range<   1,   79>(tblf, w0, w1, best, bidx); break;
        case  1: scan_range<  79,  157>(tblf, w0, w1, best, bidx); break;
        case  2: scan_range< 157,  235>(tblf, w0, w1, best, bidx); break;
        case  3: scan_range< 235,  313>(tblf, w0, w1, best, bidx); break;
        case  4: scan_range< 313,  391>(tblf, w0, w1, best, bidx); break;
        case  5: scan_range< 391,  469>(tblf, w0, w1, best, bidx); break;
        case  6: scan_range< 469,  547>(tblf, w0, w1, best, bidx); break;
        case  7: scan_range< 547,  625>(tblf, w0, w1, best, bidx); break;
        case  8: scan_range< 625,  703>(tblf, w0, w1, best, bidx); break;
        case  9: scan_range_lds< 703,  781>(lt, w0, w1, best, bidx); break;
        case 10: scan_range_lds< 781,  859>(lt, w0, w1, best, bidx); break;
        case 11: scan_range_lds< 859,  937>(lt, w0, w1, best, bidx); break;
        case 12: scan_range_lds< 937, 1014>(lt, w0, w1, best, bidx); break;
        case 13: scan_range_lds<1014, 1091>(lt, w0, w1, best, bidx); break;
        case 14: scan_range_lds<1091, 1168>(lt, w0, w1, best, bidx); break;
        case 15: scan_range_lds<1168, 1245>(lt, w0, w1, best, bidx); break;
    }

    // ---- write per-slice partials (ascending slice -> strict > keeps ties) ----
    sb[wave][lane]      = best[0];
    si[wave][lane]      = bidx[0];
    sb[wave][64 + lane] = best[1];
    si[wave][64 + lane] = bidx[1];
    __syncthreads();

    if (tid < ITEMS) {
        float bb = sb[0][tid];
        int   bi = si[0][tid];
        #pragma unroll
        for (int w = 1; w < WAVES; ++w) {
            float v  = sb[w][tid];
            int   vi = si[w][tid];
            if (v > bb) { bb = v; bi = vi; }
        }
        out[itemBase + tid] = bi;
    }
}

// ================= fallback: r4 single-kernel (proven) ====================
__device__ __forceinline__ void score_pair2(const v4f* __restrict__ tp, int p,
                                            const v2f wv[2][5],
                                            float best[2], int bidx[2]) {
    v4f a0 = tp[0], a1 = tp[1], a2 = tp[2], a3 = tp[3], a4 = tp[4];
    #pragma unroll
    for (int g = 0; g < 2; ++g) {
        v2f c0 = wv[g][0] * a0.lo;
        c0 += wv[g][1] * a0.hi; c0 += wv[g][2] * a1.lo;
        c0 += wv[g][3] * a1.hi; c0 += wv[g][4] * a2.lo;
        float s0 = c0.x + c0.y;
        v2f c1 = wv[g][0] * a2.hi;
        c1 += wv[g][1] * a3.lo; c1 += wv[g][2] * a3.hi;
        c1 += wv[g][3] * a4.lo; c1 += wv[g][4] * a4.hi;
        float s1 = c1.x + c1.y;
        float sp = s0; int ip = 2 * p;
        if (s1 > sp) { sp = s1; ip = 2 * p + 1; }
        if (sp > best[g]) { best[g] = sp; bidx[g] = ip; }
    }
}

__global__ __launch_bounds__(1024, 8) void actor_kernel(
    const int* __restrict__ wid, const int* __restrict__ pid,
    const float* __restrict__ wemb, const float* __restrict__ pemb,
    const float* __restrict__ W1, const float* __restrict__ b1,
    const float* __restrict__ W2, const float* __restrict__ b2,
    int* __restrict__ out)
{
    __shared__ v2f   sw[ITEMS][5];
    __shared__ float sb[WAVES][ITEMS];
    __shared__ int   si[WAVES][ITEMS];

    const int tid  = threadIdx.x;
    const int lane = tid & 63;
    const int wave = tid >> 6;
    const int itemBase = blockIdx.x * ITEMS;

    const v4f* __restrict__ tbl4 =
        (const v4f*)__builtin_assume_aligned(pemb, 16);

    if (wave < ITEMS / 64) {
        const int b = itemBase + wave * 64 + lane;
        const int wi = wid[b];
        const int pi = pid[b];
        const float* __restrict__ wr = wemb + wi * EMB;
        const float* __restrict__ pr = pemb + pi * EMB;
        v2f x2[STATE / 2];
        #pragma unroll
        for (int k = 0; k < EMB / 2; ++k) x2[k] = *(const v2f*)(wr + 2 * k);
        #pragma unroll
        for (int k = 0; k < EMB / 2; ++k) x2[EMB / 2 + k] = *(const v2f*)(pr + 2 * k);

        float hb[HIDDEN];
        #pragma unroll 4
        for (int j = 0; j < HIDDEN; ++j) {
            const v2f* w1r = (const v2f*)(W1 + j * STATE);
            v2f a = w1r[0] * x2[0];
            #pragma unroll
            for (int k = 1; k < STATE / 2; ++k) a += w1r[k] * x2[k];
            hb[j] = fmaxf(a.x + a.y + b1[j], 0.0f);
        }
        v2f h2[HIDDEN / 2];
        #pragma unroll
        for (int k = 0; k < HIDDEN / 2; ++k) h2[k] = (v2f){hb[2 * k], hb[2 * k + 1]};

        #pragma unroll
        for (int d = 0; d < EMB; d += 2) {
            const v2f* w2r0 = (const v2f*)(W2 + d * HIDDEN);
            const v2f* w2r1 = (const v2f*)(W2 + (d + 1) * HIDDEN);
            v2f a0 = w2r0[0] * h2[0];
            v2f a1 = w2r1[0] * h2[0];
            #pragma unroll
            for (int k = 1; k < HIDDEN / 2; ++k) { a0 += w2r0[k] * h2[k]; a1 += w2r1[k] * h2[k]; }
            sw[wave * 64 + lane][d / 2] = (v2f){a0.x + a0.y + b2[d], a1.x + a1.y + b2[d + 1]};
        }
    }
    __syncthreads();

    v2f wv[2][5];
    #pragma unroll
    for (int g = 0; g < 2; ++g) {
        #pragma unroll
        for (int k = 0; k < 5; ++k) wv[g][k] = sw[g * 64 + lane][k];
    }

    float best[2];
    int   bidx[2];
    #pragma unroll
    for (int g = 0; g < 2; ++g) { best[g] = -FLT_MAX; bidx[g] = 1; }

    if (wave == 0) {
        v2f c0v = *(const v2f*)(pemb + 10);
        v4f c1v = *(const v4f*)(pemb + 12);
        v4f c2v = *(const v4f*)(pemb + 16);
        #pragma unroll
        for (int g = 0; g < 2; ++g) {
            v2f a = wv[g][0] * c0v;
            a += wv[g][1] * c1v.lo; a += wv[g][2] * c1v.hi;
            a += wv[g][3] * c2v.lo; a += wv[g][4] * c2v.hi;
            best[g] = a.x + a.y; bidx[g] = 1;
        }
    }

    int start = (wave < 12) ? (1 + 78 * wave) : (937 + 77 * (wave - 12));
    int cnt   = (wave < 12) ? 78 : 77;
    start = __builtin_amdgcn_readfirstlane(start);
    cnt   = __builtin_amdgcn_readfirstlane(cnt);

    const v4f* tp = tbl4 + start * 5;
    #pragma unroll 4
    for (int i = 0; i < cnt; ++i, tp += 5)
        score_pair2(tp, start + i, wv, best, bidx);

    #pragma unroll
    for (int g = 0; g < 2; ++g) {
        sb[wave][g * 64 + lane] = best[g];
        si[wave][g * 64 + lane] = bidx[g];
    }
    __syncthreads();

    if (tid < ITEMS) {
        float bb = sb[0][tid];
        int   bi = si[0][tid];
        #pragma unroll
        for (int w = 1; w < WAVES; ++w) {
            float v  = sb[w][tid];
            int   vi = si[w][tid];
            if (v > bb) { bb = v; bi = vi; }
        }
        out[itemBase + tid] = bi;
    }
}

extern "C" void kernel_launch(void* const* d_in, const int* in_sizes, int n_in,
                              void* d_out, int out_size, void* d_ws, size_t ws_size,
                              hipStream_t stream) {
    const int*   wid  = (const int*)  d_in[0];
    const int*   pid  = (const int*)  d_in[1];
    const float* wemb = (const float*)d_in[2];
    const float* pemb = (const float*)d_in[3];
    const float* W1   = (const float*)d_in[4];
    const float* b1   = (const float*)d_in[5];
    const float* W2   = (const float*)d_in[6];
    const float* b2   = (const float*)d_in[7];
    int* out = (int*)d_out;

    const int B = in_sizes[0];               // 65536
    const size_t ws_needed = (size_t)B * EMB * sizeof(float);   // 2.6 MB

    if (d_ws != nullptr && ws_size >= ws_needed) {
        float* ws = (float*)d_ws;
        mlp_kernel<<<B / 256, 256, 0, stream>>>(wid, pid, wemb, pemb, W1, b1, W2, b2, ws);
        scan_kernel<<<B / ITEMS, 1024, 0, stream>>>(pemb, ws, out);
    } else {
        actor_kernel<<<B / ITEMS, 1024, 0, stream>>>(wid, pid, wemb, pemb, W1, b1, W2, b2, out);
    }
}

// Round 10
// 128.327 us; speedup vs baseline: 1.0099x; 1.0099x over previous
//
#include <hip/hip_runtime.h>
#include <float.h>

using v2f = __attribute__((ext_vector_type(2))) float;
using v4f = __attribute__((ext_vector_type(4))) float;

#define EMB 10
#define STATE 20
#define HIDDEN 40
#define NPROJ 2490
#define WAVES 16
#define ITEMS 128           // items per r8-fallback scan block
#define GITEMS 256          // items per scan4 group (64 lanes x IPL 4)
#define NSLICE 8            // grid-level table slices for scan4

// ============================ MLP kernel =================================
// One thread = one item. Writes the 10 layer-2 outputs per item to ws.
__global__ __launch_bounds__(256, 4) void mlp_kernel(
    const int* __restrict__ wid, const int* __restrict__ pid,
    const float* __restrict__ wemb, const float* __restrict__ pemb,
    const float* __restrict__ W1, const float* __restrict__ b1,
    const float* __restrict__ W2, const float* __restrict__ b2,
    float* __restrict__ ws)
{
    const int b = blockIdx.x * 256 + threadIdx.x;

    const int wi = wid[b];
    const int pi = pid[b];
    const float* __restrict__ wr = wemb + wi * EMB;
    const float* __restrict__ pr = pemb + pi * EMB;
    v2f x2[STATE / 2];
    #pragma unroll
    for (int k = 0; k < EMB / 2; ++k) x2[k] = *(const v2f*)(wr + 2 * k);
    #pragma unroll
    for (int k = 0; k < EMB / 2; ++k) x2[EMB / 2 + k] = *(const v2f*)(pr + 2 * k);

    float hb[HIDDEN];
    #pragma unroll 4
    for (int j = 0; j < HIDDEN; ++j) {
        const v2f* w1r = (const v2f*)(W1 + j * STATE);
        v2f a = w1r[0] * x2[0];
        #pragma unroll
        for (int k = 1; k < STATE / 2; ++k) a += w1r[k] * x2[k];
        hb[j] = fmaxf(a.x + a.y + b1[j], 0.0f);
    }
    v2f h2[HIDDEN / 2];
    #pragma unroll
    for (int k = 0; k < HIDDEN / 2; ++k) h2[k] = (v2f){hb[2 * k], hb[2 * k + 1]};

    v2f* wout = (v2f*)(ws + b * EMB);
    #pragma unroll
    for (int d = 0; d < EMB; d += 2) {
        const v2f* w2r0 = (const v2f*)(W2 + d * HIDDEN);
        const v2f* w2r1 = (const v2f*)(W2 + (d + 1) * HIDDEN);
        v2f a0 = w2r0[0] * h2[0];
        v2f a1 = w2r1[0] * h2[0];
        #pragma unroll
        for (int k = 1; k < HIDDEN / 2; ++k) { a0 += w2r0[k] * h2[k]; a1 += w2r1[k] * h2[k]; }
        wout[d / 2] = (v2f){a0.x + a0.y + b2[d], a1.x + a1.y + b2[d + 1]};
    }
}

// ====================== scan4: IPL=4 @ full occupancy =====================
// One row scored for FOUR items per lane. Table element t[k] is wave-uniform
// (SGPR, s_load path); per 80B pair-load a wave now does ~224 cyc of VALU
// (2x the IPL=2 ratio) -> per-wave latency tolerance doubles. Accumulation
// order per score is bitwise-identical to rounds 0-9 (even/odd chains + add).
__device__ __forceinline__ void score_row4(const float* __restrict__ tr, int row,
                                           const float w[4][10],
                                           float best[4], int bidx[4]) {
    float t0 = tr[0], t1 = tr[1], t2 = tr[2], t3 = tr[3], t4 = tr[4];
    float t5 = tr[5], t6 = tr[6], t7 = tr[7], t8 = tr[8], t9 = tr[9];
    #pragma unroll
    for (int g = 0; g < 4; ++g) {
        float e = t0 * w[g][0];
        float o = t1 * w[g][1];
        e = fmaf(t2, w[g][2], e);  o = fmaf(t3, w[g][3], o);
        e = fmaf(t4, w[g][4], e);  o = fmaf(t5, w[g][5], o);
        e = fmaf(t6, w[g][6], e);  o = fmaf(t7, w[g][7], o);
        e = fmaf(t8, w[g][8], e);  o = fmaf(t9, w[g][9], o);
        float s = e + o;
        if (s > best[g]) { best[g] = s; bidx[g] = row; }
    }
}

// Grid = 256 groups x 8 slices (blockIdx.x = group*8 + slice).
// Block = 256 threads = 4 waves; lane l owns items {l, 64+l, 128+l, 192+l}
// of its group. Slice s covers pairs [sstart, sstart+len) (ascending in s);
// the 4 waves subdivide it in ascending order. Partials -> workspace.
// 8192 total waves -> full nominal occupancy with pure-scan blocks.
__global__ __launch_bounds__(256, 6) void scan4_kernel(
    const float* __restrict__ pemb, const float* __restrict__ wsW,
    float* __restrict__ wsF, int* __restrict__ wsI)
{
    __shared__ float sb[4][GITEMS];   // 4 KB
    __shared__ int   si[4][GITEMS];   // 4 KB

    const int tid   = threadIdx.x;
    const int lane  = tid & 63;
    const int wave  = tid >> 6;              // 0..3
    const int group = blockIdx.x >> 3;
    const int slice = blockIdx.x & 7;
    const int itemBase = group * GITEMS;

    // ---- per-lane weights for its 4 items ----
    float w[4][10];
    #pragma unroll
    for (int g = 0; g < 4; ++g) {
        const float* base = wsW + (itemBase + g * 64 + lane) * EMB;
        v4f a = *(const v4f*)(base);
        v4f b = *(const v4f*)(base + 4);
        v2f c = *(const v2f*)(base + 8);
        w[g][0]=a.x; w[g][1]=a.y; w[g][2]=a.z; w[g][3]=a.w;
        w[g][4]=b.x; w[g][5]=b.y; w[g][6]=b.z; w[g][7]=b.w;
        w[g][8]=c.x; w[g][9]=c.y;
    }

    float best[4];
    int   bidx[4];
    #pragma unroll
    for (int g = 0; g < 4; ++g) { best[g] = -FLT_MAX; bidx[g] = 1; }

    // slices 0-3: 156 pairs (starts 1,157,313,469); 4-7: 155 (625,780,935,1090).
    // wave subdivision: 39/39/39/39 or 39/39/39/38 -> ascending row order.
    int sstart = (slice < 4) ? (1 + 156 * slice) : (625 + 155 * (slice - 4));
    int wstart = sstart + wave * 39;
    int wcnt   = (slice < 4) ? 39 : ((wave < 3) ? 39 : 38);
    wstart = __builtin_amdgcn_readfirstlane(wstart);
    wcnt   = __builtin_amdgcn_readfirstlane(wcnt);

    if (slice == 0 && wave == 0) {
        // row 1 alone (row 0 excluded from the table)
        score_row4(pemb + 10, 1, w, best, bidx);
    }

    const float* t = pemb + wstart * 20;
    #pragma unroll 2
    for (int i = 0; i < wcnt; ++i, t += 20) {
        score_row4(t,      2 * (wstart + i),     w, best, bidx);
        score_row4(t + 10, 2 * (wstart + i) + 1, w, best, bidx);
    }

    // ---- block reduce over 4 waves (ascending wave -> strict > keeps ties) ----
    #pragma unroll
    for (int g = 0; g < 4; ++g) {
        sb[wave][g * 64 + lane] = best[g];
        si[wave][g * 64 + lane] = bidx[g];
    }
    __syncthreads();

    // all 256 threads: one item each
    {
        float bb = sb[0][tid];
        int   bi = si[0][tid];
        #pragma unroll
        for (int wv = 1; wv < 4; ++wv) {
            float v  = sb[wv][tid];
            int   vi = si[wv][tid];
            if (v > bb) { bb = v; bi = vi; }
        }
        wsF[blockIdx.x * GITEMS + tid] = bb;
        wsI[blockIdx.x * GITEMS + tid] = bi;
    }
}

// Combine the NSLICE partials per item (ascending slice = ascending rows ->
// strict > keeps first-occurrence argmax semantics).
__global__ __launch_bounds__(256, 8) void combine_kernel(
    const float* __restrict__ wsF, const int* __restrict__ wsI,
    int* __restrict__ out)
{
    const int i = blockIdx.x * 256 + threadIdx.x;
    const int g = i >> 8;          // group
    const int l = i & 255;         // item within group
    const int base = g * NSLICE * GITEMS + l;
    float bb = wsF[base];
    int   bi = wsI[base];
    #pragma unroll
    for (int s = 1; s < NSLICE; ++s) {
        float v  = wsF[base + s * GITEMS];
        int   vi = wsI[base + s * GITEMS];
        if (v > bb) { bb = v; bi = vi; }
    }
    out[i] = bi;
}

// ============ fallback 1: r8 two-kernel scalar scan (proven 58.5us) =======
__device__ __forceinline__ void score_row(const float* __restrict__ tr, int row,
                                          const float w0[10], const float w1[10],
                                          float best[2], int bidx[2]) {
    float t0 = tr[0], t1 = tr[1], t2 = tr[2], t3 = tr[3], t4 = tr[4];
    float t5 = tr[5], t6 = tr[6], t7 = tr[7], t8 = tr[8], t9 = tr[9];

    float e0 = t0 * w0[0];
    float o0 = t1 * w0[1];
    e0 = fmaf(t2, w0[2], e0);  o0 = fmaf(t3, w0[3], o0);
    e0 = fmaf(t4, w0[4], e0);  o0 = fmaf(t5, w0[5], o0);
    e0 = fmaf(t6, w0[6], e0);  o0 = fmaf(t7, w0[7], o0);
    e0 = fmaf(t8, w0[8], e0);  o0 = fmaf(t9, w0[9], o0);
    float s0 = e0 + o0;

    float e1 = t0 * w1[0];
    float o1 = t1 * w1[1];
    e1 = fmaf(t2, w1[2], e1);  o1 = fmaf(t3, w1[3], o1);
    e1 = fmaf(t4, w1[4], e1);  o1 = fmaf(t5, w1[5], o1);
    e1 = fmaf(t6, w1[6], e1);  o1 = fmaf(t7, w1[7], o1);
    e1 = fmaf(t8, w1[8], e1);  o1 = fmaf(t9, w1[9], o1);
    float s1 = e1 + o1;

    if (s0 > best[0]) { best[0] = s0; bidx[0] = row; }
    if (s1 > best[1]) { best[1] = s1; bidx[1] = row; }
}

template <int P0, int P1>
__device__ __forceinline__ void scan_range(const float* __restrict__ tblf,
                                           const float w0[10], const float w1[10],
                                           float best[2], int bidx[2]) {
    const float* t = tblf + P0 * 20;
    #pragma unroll 4
    for (int p = P0; p < P1; ++p, t += 20) {
        score_row(t,      2 * p,     w0, w1, best, bidx);
        score_row(t + 10, 2 * p + 1, w0, w1, best, bidx);
    }
}

__global__ __launch_bounds__(1024, 8) void scan_kernel(
    const float* __restrict__ pemb, const float* __restrict__ ws,
    int* __restrict__ out)
{
    __shared__ float sb[WAVES][ITEMS];
    __shared__ int   si[WAVES][ITEMS];

    const int tid  = threadIdx.x;
    const int lane = tid & 63;
    const int wave = tid >> 6;
    const int itemBase = blockIdx.x * ITEMS;

    const float* __restrict__ tblf = pemb;

    float w0[10], w1[10];
    {
        const v4f* s0 = (const v4f*)(ws + (itemBase + lane) * EMB);
        const v2f* s0t = (const v2f*)(ws + (itemBase + lane) * EMB + 8);
        v4f a = s0[0], b = s0[1]; v2f c = s0t[0];
        w0[0]=a.x; w0[1]=a.y; w0[2]=a.z; w0[3]=a.w;
        w0[4]=b.x; w0[5]=b.y; w0[6]=b.z; w0[7]=b.w;
        w0[8]=c.x; w0[9]=c.y;
        const v4f* s1 = (const v4f*)(ws + (itemBase + 64 + lane) * EMB);
        const v2f* s1t = (const v2f*)(ws + (itemBase + 64 + lane) * EMB + 8);
        v4f d = s1[0], e = s1[1]; v2f f = s1t[0];
        w1[0]=d.x; w1[1]=d.y; w1[2]=d.z; w1[3]=d.w;
        w1[4]=e.x; w1[5]=e.y; w1[6]=e.z; w1[7]=e.w;
        w1[8]=f.x; w1[9]=f.y;
    }

    float best[2];
    int   bidx[2];
    #pragma unroll
    for (int g = 0; g < 2; ++g) { best[g] = -FLT_MAX; bidx[g] = 1; }

    if (wave == 0) {
        score_row(pemb + 10, 1, w0, w1, best, bidx);
    }

    switch (wave) {
        case  0: scan_range<   1,   79>(tblf, w0, w1, best, bidx); break;
        case  1: scan_range<  79,  157>(tblf, w0, w1, best, bidx); break;
        case  2: scan_range< 157,  235>(tblf, w0, w1, best, bidx); break;
        case  3: scan_range< 235,  313>(tblf, w0, w1, best, bidx); break;
        case  4: scan_range< 313,  391>(tblf, w0, w1, best, bidx); break;
        case  5: scan_range< 391,  469>(tblf, w0, w1, best, bidx); break;
        case  6: scan_range< 469,  547>(tblf, w0, w1, best, bidx); break;
        case  7: scan_range< 547,  625>(tblf, w0, w1, best, bidx); break;
        case  8: scan_range< 625,  703>(tblf, w0, w1, best, bidx); break;
        case  9: scan_range< 703,  781>(tblf, w0, w1, best, bidx); break;
        case 10: scan_range< 781,  859>(tblf, w0, w1, best, bidx); break;
        case 11: scan_range< 859,  937>(tblf, w0, w1, best, bidx); break;
        case 12: scan_range< 937, 1014>(tblf, w0, w1, best, bidx); break;
        case 13: scan_range<1014, 1091>(tblf, w0, w1, best, bidx); break;
        case 14: scan_range<1091, 1168>(tblf, w0, w1, best, bidx); break;
        case 15: scan_range<1168, 1245>(tblf, w0, w1, best, bidx); break;
    }

    sb[wave][lane]      = best[0];
    si[wave][lane]      = bidx[0];
    sb[wave][64 + lane] = best[1];
    si[wave][64 + lane] = bidx[1];
    __syncthreads();

    if (tid < ITEMS) {
        float bb = sb[0][tid];
        int   bi = si[0][tid];
        #pragma unroll
        for (int w = 1; w < WAVES; ++w) {
            float v  = sb[w][tid];
            int   vi = si[w][tid];
            if (v > bb) { bb = v; bi = vi; }
        }
        out[itemBase + tid] = bi;
    }
}

// ================= fallback 2: r4 single-kernel (proven) ==================
__device__ __forceinline__ void score_pair2(const v4f* __restrict__ tp, int p,
                                            const v2f wv[2][5],
                                            float best[2], int bidx[2]) {
    v4f a0 = tp[0], a1 = tp[1], a2 = tp[2], a3 = tp[3], a4 = tp[4];
    #pragma unroll
    for (int g = 0; g < 2; ++g) {
        v2f c0 = wv[g][0] * a0.lo;
        c0 += wv[g][1] * a0.hi; c0 += wv[g][2] * a1.lo;
        c0 += wv[g][3] * a1.hi; c0 += wv[g][4] * a2.lo;
        float s0 = c0.x + c0.y;
        v2f c1 = wv[g][0] * a2.hi;
        c1 += wv[g][1] * a3.lo; c1 += wv[g][2] * a3.hi;
        c1 += wv[g][3] * a4.lo; c1 += wv[g][4] * a4.hi;
        float s1 = c1.x + c1.y;
        float sp = s0; int ip = 2 * p;
        if (s1 > sp) { sp = s1; ip = 2 * p + 1; }
        if (sp > best[g]) { best[g] = sp; bidx[g] = ip; }
    }
}

__global__ __launch_bounds__(1024, 8) void actor_kernel(
    const int* __restrict__ wid, const int* __restrict__ pid,
    const float* __restrict__ wemb, const float* __restrict__ pemb,
    const float* __restrict__ W1, const float* __restrict__ b1,
    const float* __restrict__ W2, const float* __restrict__ b2,
    int* __restrict__ out)
{
    __shared__ v2f   sw[ITEMS][5];
    __shared__ float sb[WAVES][ITEMS];
    __shared__ int   si[WAVES][ITEMS];

    const int tid  = threadIdx.x;
    const int lane = tid & 63;
    const int wave = tid >> 6;
    const int itemBase = blockIdx.x * ITEMS;

    const v4f* __restrict__ tbl4 =
        (const v4f*)__builtin_assume_aligned(pemb, 16);

    if (wave < ITEMS / 64) {
        const int b = itemBase + wave * 64 + lane;
        const int wi = wid[b];
        const int pi = pid[b];
        const float* __restrict__ wr = wemb + wi * EMB;
        const float* __restrict__ pr = pemb + pi * EMB;
        v2f x2[STATE / 2];
        #pragma unroll
        for (int k = 0; k < EMB / 2; ++k) x2[k] = *(const v2f*)(wr + 2 * k);
        #pragma unroll
        for (int k = 0; k < EMB / 2; ++k) x2[EMB / 2 + k] = *(const v2f*)(pr + 2 * k);

        float hb[HIDDEN];
        #pragma unroll 4
        for (int j = 0; j < HIDDEN; ++j) {
            const v2f* w1r = (const v2f*)(W1 + j * STATE);
            v2f a = w1r[0] * x2[0];
            #pragma unroll
            for (int k = 1; k < STATE / 2; ++k) a += w1r[k] * x2[k];
            hb[j] = fmaxf(a.x + a.y + b1[j], 0.0f);
        }
        v2f h2[HIDDEN / 2];
        #pragma unroll
        for (int k = 0; k < HIDDEN / 2; ++k) h2[k] = (v2f){hb[2 * k], hb[2 * k + 1]};

        #pragma unroll
        for (int d = 0; d < EMB; d += 2) {
            const v2f* w2r0 = (const v2f*)(W2 + d * HIDDEN);
            const v2f* w2r1 = (const v2f*)(W2 + (d + 1) * HIDDEN);
            v2f a0 = w2r0[0] * h2[0];
            v2f a1 = w2r1[0] * h2[0];
            #pragma unroll
            for (int k = 1; k < HIDDEN / 2; ++k) { a0 += w2r0[k] * h2[k]; a1 += w2r1[k] * h2[k]; }
            sw[wave * 64 + lane][d / 2] = (v2f){a0.x + a0.y + b2[d], a1.x + a1.y + b2[d + 1]};
        }
    }
    __syncthreads();

    v2f wv[2][5];
    #pragma unroll
    for (int g = 0; g < 2; ++g) {
        #pragma unroll
        for (int k = 0; k < 5; ++k) wv[g][k] = sw[g * 64 + lane][k];
    }

    float best[2];
    int   bidx[2];
    #pragma unroll
    for (int g = 0; g < 2; ++g) { best[g] = -FLT_MAX; bidx[g] = 1; }

    if (wave == 0) {
        v2f c0v = *(const v2f*)(pemb + 10);
        v4f c1v = *(const v4f*)(pemb + 12);
        v4f c2v = *(const v4f*)(pemb + 16);
        #pragma unroll
        for (int g = 0; g < 2; ++g) {
            v2f a = wv[g][0] * c0v;
            a += wv[g][1] * c1v.lo; a += wv[g][2] * c1v.hi;
            a += wv[g][3] * c2v.lo; a += wv[g][4] * c2v.hi;
            best[g] = a.x + a.y; bidx[g] = 1;
        }
    }

    int start = (wave < 12) ? (1 + 78 * wave) : (937 + 77 * (wave - 12));
    int cnt   = (wave < 12) ? 78 : 77;
    start = __builtin_amdgcn_readfirstlane(start);
    cnt   = __builtin_amdgcn_readfirstlane(cnt);

    const v4f* tp = tbl4 + start * 5;
    #pragma unroll 4
    for (int i = 0; i < cnt; ++i, tp += 5)
        score_pair2(tp, start + i, wv, best, bidx);

    #pragma unroll
    for (int g = 0; g < 2; ++g) {
        sb[wave][g * 64 + lane] = best[g];
        si[wave][g * 64 + lane] = bidx[g];
    }
    __syncthreads();

    if (tid < ITEMS) {
        float bb = sb[0][tid];
        int   bi = si[0][tid];
        #pragma unroll
        for (int w = 1; w < WAVES; ++w) {
            float v  = sb[w][tid];
            int   vi = si[w][tid];
            if (v > bb) { bb = v; bi = vi; }
        }
        out[itemBase + tid] = bi;
    }
}

extern "C" void kernel_launch(void* const* d_in, const int* in_sizes, int n_in,
                              void* d_out, int out_size, void* d_ws, size_t ws_size,
                              hipStream_t stream) {
    const int*   wid  = (const int*)  d_in[0];
    const int*   pid  = (const int*)  d_in[1];
    const float* wemb = (const float*)d_in[2];
    const float* pemb = (const float*)d_in[3];
    const float* W1   = (const float*)d_in[4];
    const float* b1   = (const float*)d_in[5];
    const float* W2   = (const float*)d_in[6];
    const float* b2   = (const float*)d_in[7];
    int* out = (int*)d_out;

    const int B = in_sizes[0];               // 65536
    const int nGroups = B / GITEMS;          // 256
    const int nBlocks = nGroups * NSLICE;    // 2048

    const size_t wsW_bytes = (size_t)B * EMB * sizeof(float);           // 2.62 MB
    const size_t wsF_bytes = (size_t)nBlocks * GITEMS * sizeof(float);  // 2.10 MB
    const size_t wsI_bytes = (size_t)nBlocks * GITEMS * sizeof(int);    // 2.10 MB

    if (d_ws != nullptr && ws_size >= wsW_bytes + wsF_bytes + wsI_bytes) {
        float* wsW = (float*)d_ws;
        float* wsF = (float*)((char*)d_ws + wsW_bytes);
        int*   wsI = (int*)  ((char*)d_ws + wsW_bytes + wsF_bytes);
        mlp_kernel<<<B / 256, 256, 0, stream>>>(wid, pid, wemb, pemb, W1, b1, W2, b2, wsW);
        scan4_kernel<<<nBlocks, 256, 0, stream>>>(pemb, wsW, wsF, wsI);
        combine_kernel<<<B / 256, 256, 0, stream>>>(wsF, wsI, out);
    } else if (d_ws != nullptr && ws_size >= wsW_bytes) {
        float* ws = (float*)d_ws;
        mlp_kernel<<<B / 256, 256, 0, stream>>>(wid, pid, wemb, pemb, W1, b1, W2, b2, ws);
        scan_kernel<<<B / ITEMS, 1024, 0, stream>>>(pemb, ws, out);
    } else {
        actor_kernel<<<B / ITEMS, 1024, 0, stream>>>(wid, pid, wemb, pemb, W1, b1, W2, b2, out);
    }
}